// Round 13
// baseline (840.068 us; speedup 1.0000x reference)
//
#include <hip/hip_runtime.h>

// MAF forward: 32 autoregressive MADE steps, fully fused. N=65536, D=32, H=1024, C=64.
// R12 = R11 (register-chained GEMM1->tanh->GEMM2, W2 k-permuted, f32 partials,
//   exp2-domain log-scale, 2 barriers/step, 1 blk/CU) with the partial path
//   rebuilt around f32x4 quads to cut LDS instruction count ~4x:
//   - GEMM2: ONE ds_write_b128 per (sh,ct)  (acc[0..3] = 4 consecutive samples)
//   - epilogue: 512 threads, thread=(sample-quad sq, col c); 16 ds_read_b128
//     (contiguous, bank-uniform), f32x4 add tree, shfl_xor(1) shift<->ls swap,
//     even-c threads do 4x exp2 + ybf/out writes. log_det via even-lane shfl tree.
// ws layout (bf16 as u16):
//   [0      .. 32768)  W1mT  [h=1024][d=32]   = W1[d][h]*mask1 * 2log2e
//   [32768  .. 98304)  W2mTp [c=64][q=1024]   = W2[perm(q)][c]*mask2 * (c odd ? log2e : 1)
//   [98304  ..163840)  WcT   [h=1024][c=64]   = Wc[c][h] * 2log2e

#define NS 65536
#define HH 1024
#define K2LOG2E 2.885390082f
#define KLOG2E 1.4426950408889634f
#define KLN2 0.6931471805599453f

typedef __attribute__((ext_vector_type(8))) short short8;
typedef __attribute__((ext_vector_type(4))) float f32x4;

__device__ inline unsigned short f2bf(float f) {
  unsigned int u = __builtin_bit_cast(unsigned int, f);
  u += 0x7fffu + ((u >> 16) & 1u);          // RNE
  return (unsigned short)(u >> 16);
}
__device__ inline unsigned int cvt_pk_bf16(float lo, float hi) {
  unsigned int r;
  asm("v_cvt_pk_bf16_f32 %0, %1, %2" : "=v"(r) : "v"(lo), "v"(hi));
  return r;
}
// input pre-scaled by 2log2e: tanh = 1 - 2/(1+exp2(z)); saturates for |z| large
__device__ inline float tanh_pre(float z) {
  float t = __builtin_amdgcn_exp2f(z);
  float r = __builtin_amdgcn_rcpf(t + 1.0f);
  return fmaf(-2.0f, r, 1.0f);
}

__global__ void maf_prep(const float* __restrict__ W1, const float* __restrict__ Wc,
                         const float* __restrict__ W2, unsigned short* __restrict__ ws) {
  int t = blockIdx.x * blockDim.x + threadIdx.x;     // 0 .. 163839
  if (t < 32768) {                                   // W1mT [h][d], scaled
    int h = t >> 5, d = t & 31;
    int deg = h % 31 + 1;                            // hid_deg
    float v = (deg >= d + 1) ? W1[(size_t)d * HH + h] * K2LOG2E : 0.f;
    ws[t] = f2bf(v);
  } else if (t < 98304) {                            // W2mTp [c][q], k-permuted
    int i = t - 32768;
    int c = i >> 10, q = i & 1023;
    int wv = q >> 6, m = (q >> 5) & 1, lk = (q >> 3) & 3, jp = (q >> 2) & 1, r = q & 3;
    int h = wv * 64 + (2 * m + jp) * 16 + 4 * lk + r;
    int deg = h % 31 + 1;
    float v = (((c >> 1) + 1) > deg) ? W2[(size_t)h * 64 + c] : 0.f;
    if (c & 1) v *= KLOG2E;                          // log-scale cols in log2 domain
    ws[t] = f2bf(v);
  } else {                                           // WcT [h][c], scaled
    int i = t - 98304;
    int h = i >> 6, c = i & 63;
    ws[t] = f2bf(Wc[(size_t)c * HH + h] * K2LOG2E);
  }
}

__global__ __launch_bounds__(1024, 4) void maf_main(
    const float* __restrict__ x, const float* __restrict__ ctx,
    const float* __restrict__ b1, const float* __restrict__ b2,
    const unsigned short* __restrict__ ws, float* __restrict__ out)
{
  // LDS: 2560 + 139264 = 141824 B -> 1 block/CU (4 waves/EU, 128-reg cap)
  __shared__ __align__(16) unsigned short ybf[32][40];  // y bf16 [s][d]
  __shared__ f32x4 PpwQ[16][8][68];                     // partials [w][sample-quad][col]

  const unsigned short* W1mT  = ws;            // [1024][32]
  const unsigned short* W2mTp = ws + 32768;    // [64][1024] (k-permuted)
  const unsigned short* WcT   = ws + 98304;    // [1024][64]

  const int tid  = threadIdx.x;
  const int lane = tid & 63;
  const int w    = tid >> 6;        // wave 0..15: owns h-chunk [64w, 64w+64)
  const int l15  = lane & 15;
  const int lk   = lane >> 4;       // 0..3
  const int s0   = blockIdx.x * 32;

  // zero y
  if (tid < 640) reinterpret_cast<unsigned int*>(&ybf[0][0])[tid] = 0u;

  // ---- ctx B-fragments from global (f32 -> bf16 via cvt_pk) ----
  short8 cf[2][2];
#pragma unroll
  for (int sh = 0; sh < 2; ++sh)
#pragma unroll
    for (int kc = 0; kc < 2; ++kc) {
      const float* cp = ctx + (size_t)(s0 + sh * 16 + l15) * 64 + kc * 32 + lk * 8;
      f32x4 a = *reinterpret_cast<const f32x4*>(cp);
      f32x4 b = *reinterpret_cast<const f32x4*>(cp + 4);
      union { short8 s; unsigned int u[4]; } t;
      t.u[0] = cvt_pk_bf16(a[0], a[1]);
      t.u[1] = cvt_pk_bf16(a[2], a[3]);
      t.u[2] = cvt_pk_bf16(b[0], b[1]);
      t.u[3] = cvt_pk_bf16(b[2], b[3]);
      cf[sh][kc] = t.s;
    }

  // ---- WcH^T + b1 (both pre-scaled) for this wave's 64 h-rows; f32 (32 regs) ----
  f32x4 wch[2][4];
#pragma unroll
  for (int j = 0; j < 4; ++j) {
    int h0 = w * 64 + j * 16;
    f32x4 binit = *reinterpret_cast<const f32x4*>(b1 + h0 + 4 * lk);
    binit *= K2LOG2E;
#pragma unroll
    for (int sh = 0; sh < 2; ++sh) {
      f32x4 acc = binit;
#pragma unroll
      for (int kc = 0; kc < 2; ++kc) {
        short8 af = *reinterpret_cast<const short8*>(WcT + (size_t)(h0 + l15) * 64 + kc * 32 + lk * 8);
        acc = __builtin_amdgcn_mfma_f32_16x16x32_bf16(af, cf[sh][kc], acc, 0, 0, 0);
      }
      wch[sh][j] = acc;
    }
  }

  // ---- W1 A-fragments, register-resident (16 regs) ----
  short8 w1f[4];
#pragma unroll
  for (int j = 0; j < 4; ++j)
    w1f[j] = *reinterpret_cast<const short8*>(W1mT + (size_t)(w * 64 + j * 16 + l15) * 32 + lk * 8);

  // ---- W2 B-fragments for own h-chunk, all 64 c (32 regs): w2f[ct][m] ----
  short8 w2f[4][2];
#pragma unroll
  for (int ct = 0; ct < 4; ++ct)
#pragma unroll
    for (int m = 0; m < 2; ++m)
      w2f[ct][m] = *reinterpret_cast<const short8*>(
          W2mTp + (size_t)(16 * ct + l15) * 1024 + w * 64 + m * 32 + lk * 8);

  // ---- epilogue role (512 threads): thread -> (sample-quad sq, col c) ----
  const int sq = (tid >> 6) & 7, ec = tid & 63;   // wave sq, lane ec == col
  const int ed = ec >> 1;                          // dim for even-c threads
  float xr[4];
  float b2c = 0.f;
  if (tid < 512) {
    b2c = (ec & 1) ? b2[ec] * KLOG2E : b2[ec];
#pragma unroll
    for (int i = 0; i < 4; ++i)
      xr[i] = x[(size_t)(s0 + 4 * sq + i) * 32 + ed];
  }
  f32x4 lsl4 = {0.f, 0.f, 0.f, 0.f};

  __syncthreads();

#pragma unroll 1
  for (int step = 0; step < 32; ++step) {
    // ---- GEMM1 + tanh, all in registers; pa[sh][j] = packed bf16 hid frags ----
    short8 yb0 = *reinterpret_cast<const short8*>(&ybf[l15][lk * 8]);
    short8 yb1 = *reinterpret_cast<const short8*>(&ybf[16 + l15][lk * 8]);
    unsigned int pa[2][4][2];
#pragma unroll
    for (int j = 0; j < 4; ++j) {
      f32x4 c0 = __builtin_amdgcn_mfma_f32_16x16x32_bf16(w1f[j], yb0, wch[0][j], 0, 0, 0);
      f32x4 c1 = __builtin_amdgcn_mfma_f32_16x16x32_bf16(w1f[j], yb1, wch[1][j], 0, 0, 0);
      pa[0][j][0] = cvt_pk_bf16(tanh_pre(c0[0]), tanh_pre(c0[1]));
      pa[0][j][1] = cvt_pk_bf16(tanh_pre(c0[2]), tanh_pre(c0[3]));
      pa[1][j][0] = cvt_pk_bf16(tanh_pre(c1[0]), tanh_pre(c1[1]));
      pa[1][j][1] = cvt_pk_bf16(tanh_pre(c1[2]), tanh_pre(c1[3]));
    }

    // ---- GEMM2; sh-outer; ONE b128 write per (sh,ct): acc = 4 consecutive samples ----
#pragma unroll
    for (int sh = 0; sh < 2; ++sh) {
      union { unsigned int u[4]; short8 s; } a0, a1;
      a0.u[0] = pa[sh][0][0]; a0.u[1] = pa[sh][0][1];
      a0.u[2] = pa[sh][1][0]; a0.u[3] = pa[sh][1][1];
      a1.u[0] = pa[sh][2][0]; a1.u[1] = pa[sh][2][1];
      a1.u[2] = pa[sh][3][0]; a1.u[3] = pa[sh][3][1];
#pragma unroll
      for (int ct = 0; ct < 4; ++ct) {
        f32x4 acc = {0.f, 0.f, 0.f, 0.f};
        acc = __builtin_amdgcn_mfma_f32_16x16x32_bf16(a0.s, w2f[ct][0], acc, 0, 0, 0);
        acc = __builtin_amdgcn_mfma_f32_16x16x32_bf16(a1.s, w2f[ct][1], acc, 0, 0, 0);
        PpwQ[w][4 * sh + lk][16 * ct + l15] = acc;   // samples 4*(4sh+lk)+0..3
      }
    }
    __syncthreads();

    // ---- epilogue (512 threads): reduce 16 slices as f32x4, swap, 4x exp2 ----
    if (tid < 512) {
      f32x4 u0 = PpwQ[0][sq][ec] + PpwQ[1][sq][ec];
      f32x4 u1 = PpwQ[2][sq][ec] + PpwQ[3][sq][ec];
      f32x4 u2 = PpwQ[4][sq][ec] + PpwQ[5][sq][ec];
      f32x4 u3 = PpwQ[6][sq][ec] + PpwQ[7][sq][ec];
      f32x4 u4 = PpwQ[8][sq][ec] + PpwQ[9][sq][ec];
      f32x4 u5 = PpwQ[10][sq][ec] + PpwQ[11][sq][ec];
      f32x4 u6 = PpwQ[12][sq][ec] + PpwQ[13][sq][ec];
      f32x4 u7 = PpwQ[14][sq][ec] + PpwQ[15][sq][ec];
      u0 += u4; u1 += u5; u2 += u6; u3 += u7;
      u0 += u2; u1 += u3;
      u0 += u1;
      u0 += (f32x4){b2c, b2c, b2c, b2c};
      f32x4 po;                                   // partner column (c^1)
#pragma unroll
      for (int i = 0; i < 4; ++i) po[i] = __shfl_xor(u0[i], 1);
      if (!(ec & 1)) {                            // own=shift, partner=ls (log2)
        const bool last = (step == 31);
#pragma unroll
        for (int i = 0; i < 4; ++i) {
          float yv = fmaf(xr[i], __builtin_amdgcn_exp2f(po[i]), u0[i]);
          ybf[4 * sq + i][ed] = f2bf(yv);
          if (last) out[(size_t)(s0 + 4 * sq + i) * 32 + ed] = yv;
        }
        if (last) lsl4 = po * KLN2;               // natural-log ls, samples 4sq..4sq+3
      }
    }
    __syncthreads();
  }

  // ---- log_det: sum ls over d (even lanes of epilogue waves hold d = lane/2) ----
  if (tid < 512) {
    f32x4 v = lsl4;                               // odd-c lanes carry 0
#pragma unroll
    for (int off = 2; off <= 32; off <<= 1)
#pragma unroll
      for (int i = 0; i < 4; ++i) v[i] += __shfl_xor(v[i], off);
    if (ec == 0) {
#pragma unroll
      for (int i = 0; i < 4; ++i)
        out[(size_t)NS * 32 + s0 + 4 * sq + i] = v[i];
    }
  }
}

extern "C" void kernel_launch(void* const* d_in, const int* in_sizes, int n_in,
                              void* d_out, int out_size, void* d_ws, size_t ws_size,
                              hipStream_t stream) {
  (void)in_sizes; (void)n_in; (void)out_size; (void)ws_size;
  const float* x   = (const float*)d_in[0];
  const float* ctx = (const float*)d_in[1];
  const float* W1  = (const float*)d_in[2];
  const float* b1  = (const float*)d_in[3];
  const float* Wc  = (const float*)d_in[4];
  const float* W2  = (const float*)d_in[5];
  const float* b2  = (const float*)d_in[6];
  unsigned short* ws = (unsigned short*)d_ws;
  float* out = (float*)d_out;

  maf_prep<<<640, 256, 0, stream>>>(W1, Wc, W2, ws);
  maf_main<<<2048, 1024, 0, stream>>>(x, ctx, b1, b2, ws, out);
}

// Round 14
// 751.337 us; speedup vs baseline: 1.1181x; 1.1181x over previous
//
#include <hip/hip_runtime.h>

// MAF forward: 32 autoregressive MADE steps, fully fused. N=65536, D=32, H=1024, C=64.
// R13 = R11 verbatim (best verified: 751us). R12's quad-epilogue spilled
//   (WRITE_SIZE 8.4->98.5 MB, FETCH +6.4 GB) and its LDS-inst-count premise was
//   wrong (LDS is byte-throughput-bound: b128 = 2x b64 cycles). Reverted.
// Structure: register-chained GEMM1->tanh->GEMM2 (W2 k-permuted so GEMM1's MFMA
//   C-registers are GEMM2's A-fragments), f32 per-wave-slice partials in LDS +
//   f32x2 tree read-reduce, exp2-domain log-scale, 2 barriers/step, 1 blk/CU.
// ws layout (bf16 as u16):
//   [0      .. 32768)  W1mT  [h=1024][d=32]   = W1[d][h]*mask1 * 2log2e
//   [32768  .. 98304)  W2mTp [c=64][q=1024]   = W2[perm(q)][c]*mask2 * (c odd ? log2e : 1)
//   [98304  ..163840)  WcT   [h=1024][c=64]   = Wc[c][h] * 2log2e

#define NS 65536
#define HH 1024
#define K2LOG2E 2.885390082f
#define KLOG2E 1.4426950408889634f
#define KLN2 0.6931471805599453f

typedef __attribute__((ext_vector_type(8))) short short8;
typedef __attribute__((ext_vector_type(4))) float f32x4;
typedef __attribute__((ext_vector_type(2))) float f32x2;

__device__ inline unsigned short f2bf(float f) {
  unsigned int u = __builtin_bit_cast(unsigned int, f);
  u += 0x7fffu + ((u >> 16) & 1u);          // RNE
  return (unsigned short)(u >> 16);
}
__device__ inline unsigned int cvt_pk_bf16(float lo, float hi) {
  unsigned int r;
  asm("v_cvt_pk_bf16_f32 %0, %1, %2" : "=v"(r) : "v"(lo), "v"(hi));
  return r;
}
// input pre-scaled by 2log2e: tanh = 1 - 2/(1+exp2(z)); saturates for |z| large
__device__ inline float tanh_pre(float z) {
  float t = __builtin_amdgcn_exp2f(z);
  float r = __builtin_amdgcn_rcpf(t + 1.0f);
  return fmaf(-2.0f, r, 1.0f);
}

__global__ void maf_prep(const float* __restrict__ W1, const float* __restrict__ Wc,
                         const float* __restrict__ W2, unsigned short* __restrict__ ws) {
  int t = blockIdx.x * blockDim.x + threadIdx.x;     // 0 .. 163839
  if (t < 32768) {                                   // W1mT [h][d], scaled
    int h = t >> 5, d = t & 31;
    int deg = h % 31 + 1;                            // hid_deg
    float v = (deg >= d + 1) ? W1[(size_t)d * HH + h] * K2LOG2E : 0.f;
    ws[t] = f2bf(v);
  } else if (t < 98304) {                            // W2mTp [c][q], k-permuted
    int i = t - 32768;
    int c = i >> 10, q = i & 1023;
    int wv = q >> 6, m = (q >> 5) & 1, lk = (q >> 3) & 3, jp = (q >> 2) & 1, r = q & 3;
    int h = wv * 64 + (2 * m + jp) * 16 + 4 * lk + r;
    int deg = h % 31 + 1;
    float v = (((c >> 1) + 1) > deg) ? W2[(size_t)h * 64 + c] : 0.f;
    if (c & 1) v *= KLOG2E;                          // log-scale cols in log2 domain
    ws[t] = f2bf(v);
  } else {                                           // WcT [h][c], scaled
    int i = t - 98304;
    int h = i >> 6, c = i & 63;
    ws[t] = f2bf(Wc[(size_t)c * HH + h] * K2LOG2E);
  }
}

__global__ __launch_bounds__(1024, 4) void maf_main(
    const float* __restrict__ x, const float* __restrict__ ctx,
    const float* __restrict__ b1, const float* __restrict__ b2,
    const unsigned short* __restrict__ ws, float* __restrict__ out)
{
  // LDS: 2560 + 139264 = 141824 B -> 1 block/CU (4 waves/EU, 128-reg cap)
  __shared__ __align__(16) unsigned short ybf[32][40];  // y bf16 [s][d]
  __shared__ __align__(16) float Ppw[16][32][68];       // per-wave P partials [w][s][c]

  const unsigned short* W1mT  = ws;            // [1024][32]
  const unsigned short* W2mTp = ws + 32768;    // [64][1024] (k-permuted)
  const unsigned short* WcT   = ws + 98304;    // [1024][64]

  const int tid  = threadIdx.x;
  const int lane = tid & 63;
  const int w    = tid >> 6;        // wave 0..15: owns h-chunk [64w, 64w+64)
  const int l15  = lane & 15;
  const int lk   = lane >> 4;       // 0..3
  const int s0   = blockIdx.x * 32;

  // zero y
  if (tid < 640) reinterpret_cast<unsigned int*>(&ybf[0][0])[tid] = 0u;

  // ---- ctx B-fragments from global (f32 -> bf16 via cvt_pk) ----
  short8 cf[2][2];
#pragma unroll
  for (int sh = 0; sh < 2; ++sh)
#pragma unroll
    for (int kc = 0; kc < 2; ++kc) {
      const float* cp = ctx + (size_t)(s0 + sh * 16 + l15) * 64 + kc * 32 + lk * 8;
      f32x4 a = *reinterpret_cast<const f32x4*>(cp);
      f32x4 b = *reinterpret_cast<const f32x4*>(cp + 4);
      union { short8 s; unsigned int u[4]; } t;
      t.u[0] = cvt_pk_bf16(a[0], a[1]);
      t.u[1] = cvt_pk_bf16(a[2], a[3]);
      t.u[2] = cvt_pk_bf16(b[0], b[1]);
      t.u[3] = cvt_pk_bf16(b[2], b[3]);
      cf[sh][kc] = t.s;
    }

  // ---- WcH^T + b1 (both pre-scaled) for this wave's 64 h-rows; f32 (32 regs) ----
  f32x4 wch[2][4];
#pragma unroll
  for (int j = 0; j < 4; ++j) {
    int h0 = w * 64 + j * 16;
    f32x4 binit = *reinterpret_cast<const f32x4*>(b1 + h0 + 4 * lk);
    binit *= K2LOG2E;
#pragma unroll
    for (int sh = 0; sh < 2; ++sh) {
      f32x4 acc = binit;
#pragma unroll
      for (int kc = 0; kc < 2; ++kc) {
        short8 af = *reinterpret_cast<const short8*>(WcT + (size_t)(h0 + l15) * 64 + kc * 32 + lk * 8);
        acc = __builtin_amdgcn_mfma_f32_16x16x32_bf16(af, cf[sh][kc], acc, 0, 0, 0);
      }
      wch[sh][j] = acc;
    }
  }

  // ---- W1 A-fragments, register-resident (16 regs) ----
  short8 w1f[4];
#pragma unroll
  for (int j = 0; j < 4; ++j)
    w1f[j] = *reinterpret_cast<const short8*>(W1mT + (size_t)(w * 64 + j * 16 + l15) * 32 + lk * 8);

  // ---- W2 B-fragments for own h-chunk, all 64 c (32 regs): w2f[ct][m] ----
  short8 w2f[4][2];
#pragma unroll
  for (int ct = 0; ct < 4; ++ct)
#pragma unroll
    for (int m = 0; m < 2; ++m)
      w2f[ct][m] = *reinterpret_cast<const short8*>(
          W2mTp + (size_t)(16 * ct + l15) * 1024 + w * 64 + m * 32 + lk * 8);

  // ---- epilogue role: thread -> (sample se, dim de) ----
  const int se = tid >> 5, de = tid & 31;
  const float xv  = x[(size_t)(s0 + se) * 32 + de];
  const float b2e = b2[2 * de];
  const float b2o = b2[2 * de + 1] * KLOG2E;     // log2 domain
  float ls_last = 0.f;

  __syncthreads();

#pragma unroll 1
  for (int step = 0; step < 32; ++step) {
    // ---- GEMM1 + tanh, all in registers; pa[sh][j] = packed bf16 hid frags ----
    short8 yb0 = *reinterpret_cast<const short8*>(&ybf[l15][lk * 8]);
    short8 yb1 = *reinterpret_cast<const short8*>(&ybf[16 + l15][lk * 8]);
    unsigned int pa[2][4][2];
#pragma unroll
    for (int j = 0; j < 4; ++j) {
      f32x4 c0 = __builtin_amdgcn_mfma_f32_16x16x32_bf16(w1f[j], yb0, wch[0][j], 0, 0, 0);
      f32x4 c1 = __builtin_amdgcn_mfma_f32_16x16x32_bf16(w1f[j], yb1, wch[1][j], 0, 0, 0);
      pa[0][j][0] = cvt_pk_bf16(tanh_pre(c0[0]), tanh_pre(c0[1]));
      pa[0][j][1] = cvt_pk_bf16(tanh_pre(c0[2]), tanh_pre(c0[3]));
      pa[1][j][0] = cvt_pk_bf16(tanh_pre(c1[0]), tanh_pre(c1[1]));
      pa[1][j][1] = cvt_pk_bf16(tanh_pre(c1[2]), tanh_pre(c1[3]));
    }

    // ---- GEMM2 over own h-chunk from registers; sh-outer so A-frags built once ----
#pragma unroll
    for (int sh = 0; sh < 2; ++sh) {
      union { unsigned int u[4]; short8 s; } a0, a1;
      a0.u[0] = pa[sh][0][0]; a0.u[1] = pa[sh][0][1];
      a0.u[2] = pa[sh][1][0]; a0.u[3] = pa[sh][1][1];
      a1.u[0] = pa[sh][2][0]; a1.u[1] = pa[sh][2][1];
      a1.u[2] = pa[sh][3][0]; a1.u[3] = pa[sh][3][1];
#pragma unroll
      for (int ct = 0; ct < 4; ++ct) {
        f32x4 acc = {0.f, 0.f, 0.f, 0.f};
        acc = __builtin_amdgcn_mfma_f32_16x16x32_bf16(a0.s, w2f[ct][0], acc, 0, 0, 0);
        acc = __builtin_amdgcn_mfma_f32_16x16x32_bf16(a1.s, w2f[ct][1], acc, 0, 0, 0);
#pragma unroll
        for (int r = 0; r < 4; ++r)
          Ppw[w][16 * sh + 4 * lk + r][16 * ct + l15] = acc[r];
      }
    }
    __syncthreads();

    // ---- epilogue: thread (se, de): f32x2 tree-reduce 16 slices ----
    {
      f32x2 t0, t1, t2, t3, t4, t5, t6, t7;
      t0 = *reinterpret_cast<const f32x2*>(&Ppw[0][se][2 * de])
         + *reinterpret_cast<const f32x2*>(&Ppw[1][se][2 * de]);
      t1 = *reinterpret_cast<const f32x2*>(&Ppw[2][se][2 * de])
         + *reinterpret_cast<const f32x2*>(&Ppw[3][se][2 * de]);
      t2 = *reinterpret_cast<const f32x2*>(&Ppw[4][se][2 * de])
         + *reinterpret_cast<const f32x2*>(&Ppw[5][se][2 * de]);
      t3 = *reinterpret_cast<const f32x2*>(&Ppw[6][se][2 * de])
         + *reinterpret_cast<const f32x2*>(&Ppw[7][se][2 * de]);
      t4 = *reinterpret_cast<const f32x2*>(&Ppw[8][se][2 * de])
         + *reinterpret_cast<const f32x2*>(&Ppw[9][se][2 * de]);
      t5 = *reinterpret_cast<const f32x2*>(&Ppw[10][se][2 * de])
         + *reinterpret_cast<const f32x2*>(&Ppw[11][se][2 * de]);
      t6 = *reinterpret_cast<const f32x2*>(&Ppw[12][se][2 * de])
         + *reinterpret_cast<const f32x2*>(&Ppw[13][se][2 * de]);
      t7 = *reinterpret_cast<const f32x2*>(&Ppw[14][se][2 * de])
         + *reinterpret_cast<const f32x2*>(&Ppw[15][se][2 * de]);
      t0 += t4; t1 += t5; t2 += t6; t3 += t7;
      t0 += t2; t1 += t3;
      t0 += t1;
      float shv = t0[0] + b2e;
      float lsv = t0[1] + b2o;                       // log2 domain
      float yv = fmaf(xv, __builtin_amdgcn_exp2f(lsv), shv);
      ybf[se][de] = f2bf(yv);
      if (step == 31) {
        out[(size_t)(s0 + se) * 32 + de] = yv;
        ls_last = lsv * KLN2;                        // back to natural log
      }
    }
    __syncthreads();
  }

  // ---- log_det: reduce ls over de within each 32-lane group ----
  float v = ls_last;
  v += __shfl_xor(v, 1);
  v += __shfl_xor(v, 2);
  v += __shfl_xor(v, 4);
  v += __shfl_xor(v, 8);
  v += __shfl_xor(v, 16);
  if (de == 0) out[(size_t)NS * 32 + s0 + se] = v;
}

extern "C" void kernel_launch(void* const* d_in, const int* in_sizes, int n_in,
                              void* d_out, int out_size, void* d_ws, size_t ws_size,
                              hipStream_t stream) {
  (void)in_sizes; (void)n_in; (void)out_size; (void)ws_size;
  const float* x   = (const float*)d_in[0];
  const float* ctx = (const float*)d_in[1];
  const float* W1  = (const float*)d_in[2];
  const float* b1  = (const float*)d_in[3];
  const float* Wc  = (const float*)d_in[4];
  const float* W2  = (const float*)d_in[5];
  const float* b2  = (const float*)d_in[6];
  unsigned short* ws = (unsigned short*)d_ws;
  float* out = (float*)d_out;

  maf_prep<<<640, 256, 0, stream>>>(W1, Wc, W2, ws);
  maf_main<<<2048, 1024, 0, stream>>>(x, ctx, b1, b2, ws, out);
}

// Round 15
// 229.950 us; speedup vs baseline: 3.6533x; 3.2674x over previous
//
#include <hip/hip_runtime.h>

// MAF forward, single-pass autoregressive rewrite. N=65536, D=32, H=1024, C=64.
// Key identity: after scan step s, y dims <= s are final => final output equals ONE
// pass: for t=0..31: emit y[t] from P (partial sums over hid groups deg<=t), then
// compute hid with deg==t+1 ONCE (from final y[0..t]) and accumulate into P.
// 32x fewer tanh, ~16x fewer MFMA FLOPs than the reference scan.
// Structure: 256 blocks x 1024 thr (1/CU), 16 waves x 16 samples, P[16s][64c] in
// MFMA accumulators for the entire loop (no LDS partial round-trip). Per micro-step:
// emit (acc extract + shfl pair-swap + exp2) -> bar -> GEMM1 (deg-group t: 3 h-tiles,
// K=96 = masked-y(32) + ctx(64), b1 C-init) -> tanh -> register-chained P-accum
// (W2 degree-bucketed + q-permuted so GEMM1 C-regs are P's A-frags) -> bar.
// ws layout (bf16 u16):
//   [0      ..  32768)  W1mT [h=1024][d=32] = W1[d][h]*mask1 * 2log2e
//   [32768  ..  98304)  WcT  [h=1024][c=64] = Wc[c][h] * 2log2e
//   [98304  .. 225280)  W2g  [c=64][g=31][kw=64]  degree-bucketed, q-permuted,
//                       zero-padded; ls cols * log2e
//   [225280 .. 227264)  b1g  [g=31][slot=64] bf16 = b1[h]*2log2e (0 pads)

#define NS 65536
#define K2LOG2E 2.885390082f
#define KLOG2E 1.4426950408889634f
#define KLN2 0.6931471805599453f

typedef __attribute__((ext_vector_type(8))) short short8;
typedef __attribute__((ext_vector_type(4))) float f32x4;

__device__ inline unsigned short f2bf(float f) {
  unsigned int u = __builtin_bit_cast(unsigned int, f);
  u += 0x7fffu + ((u >> 16) & 1u);          // RNE
  return (unsigned short)(u >> 16);
}
__device__ inline unsigned int cvt_pk_bf16(float lo, float hi) {
  unsigned int r;
  asm("v_cvt_pk_bf16_f32 %0, %1, %2" : "=v"(r) : "v"(lo), "v"(hi));
  return r;
}
__device__ inline float bf2f(unsigned short s) {
  return __builtin_bit_cast(float, (unsigned int)s << 16);
}
// input pre-scaled by 2log2e: tanh = 1 - 2/(1+exp2(z))
__device__ inline float tanh_pre(float z) {
  float t = __builtin_amdgcn_exp2f(z);
  float r = __builtin_amdgcn_rcpf(t + 1.0f);
  return fmaf(-2.0f, r, 1.0f);
}

__global__ void maf_prep(const float* __restrict__ W1, const float* __restrict__ Wc,
                         const float* __restrict__ W2, const float* __restrict__ b1,
                         unsigned short* __restrict__ ws) {
  int t = blockIdx.x * blockDim.x + threadIdx.x;
  if (t < 32768) {                                   // W1mT [h][d], masked+scaled
    int h = t >> 5, d = t & 31;
    int deg = h % 31 + 1;
    float v = (deg >= d + 1) ? W1[(size_t)d * 1024 + h] * K2LOG2E : 0.f;
    ws[t] = f2bf(v);
  } else if (t < 98304) {                            // WcT [h][c], scaled
    int i = t - 32768;
    int h = i >> 6, c = i & 63;
    ws[t] = f2bf(Wc[(size_t)c * 1024 + h] * K2LOG2E);
  } else if (t < 225280) {                           // W2g [c][g][kw]
    int i = t - 98304;
    int c = i / 1984, kpos = i % 1984;
    int g = kpos >> 6, kw = kpos & 63;
    int m = kw >> 5, rem = kw & 31;
    int lkk = rem >> 3, jp = (rem >> 2) & 1, r = rem & 3;
    int slot = (2 * m + jp) * 16 + 4 * lkk + r;      // q-perm -> slot within group
    int cnt = (g == 0) ? 34 : 33;
    float v = 0.f;
    if (slot < cnt) {
      int h = g + 31 * slot;                         // deg(h) == g+1
      int d = c >> 1;
      if (d > g) {                                   // mask2: out_deg > hid_deg
        v = W2[(size_t)h * 64 + c];
        if (c & 1) v *= KLOG2E;                      // ls cols in log2 domain
      }
    }
    ws[t] = f2bf(v);
  } else if (t < 227264) {                           // b1g [g][slot]
    int i = t - 225280;
    int g = i >> 6, slot = i & 63;
    int cnt = (g == 0) ? 34 : 33;
    float v = (slot < cnt) ? b1[g + 31 * slot] * K2LOG2E : 0.f;
    ws[t] = f2bf(v);
  }
}

__global__ __launch_bounds__(1024, 4) void maf_main(
    const float* __restrict__ x, const float* __restrict__ ctx,
    const float* __restrict__ b2, const unsigned short* __restrict__ ws,
    float* __restrict__ out)
{
  // LDS: 20480 + 36864 + 33280 = 90624 B -> 1 block/CU
  __shared__ __align__(16) unsigned short ybf[256][40];   // y bf16 [s][d]
  __shared__ __align__(16) unsigned short ctxb[256][72];  // ctx bf16 [s][c]
  __shared__ __align__(16) float xT[32][260];             // x transposed [d][s]

  const unsigned short* W1mT = ws;             // [1024][32]
  const unsigned short* WcT  = ws + 32768;     // [1024][64]
  const unsigned short* W2g  = ws + 98304;     // [64][1984]
  const unsigned short* b1g  = ws + 225280;    // [1984]

  const int tid  = threadIdx.x;
  const int lane = tid & 63;
  const int w    = tid >> 6;        // wave 0..15: samples [16w, 16w+16)
  const int l15  = lane & 15;
  const int lk   = lane >> 4;
  const int s0   = blockIdx.x * 256;

  // ---- stage: zero ybf ----
  for (int i = tid; i < 5120; i += 1024)
    reinterpret_cast<unsigned int*>(&ybf[0][0])[i] = 0u;
  // ---- stage ctx (f32 -> bf16) ----
  {
    int s = tid >> 2, q = tid & 3;
    const float* cp = ctx + (size_t)(s0 + s) * 64 + 16 * q;
    unsigned int pk[8];
#pragma unroll
    for (int i = 0; i < 4; ++i) {
      f32x4 v = *reinterpret_cast<const f32x4*>(cp + 4 * i);
      pk[2 * i]     = cvt_pk_bf16(v[0], v[1]);
      pk[2 * i + 1] = cvt_pk_bf16(v[2], v[3]);
    }
    unsigned int* dst = reinterpret_cast<unsigned int*>(&ctxb[s][16 * q]);
#pragma unroll
    for (int i = 0; i < 8; ++i) dst[i] = pk[i];
  }
  // ---- stage xT ----
  {
    int s = tid >> 2, q = tid & 3;
    const float* xp = x + (size_t)(s0 + s) * 32 + 8 * q;
    f32x4 v0 = *reinterpret_cast<const f32x4*>(xp);
    f32x4 v1 = *reinterpret_cast<const f32x4*>(xp + 4);
#pragma unroll
    for (int i = 0; i < 4; ++i) xT[8 * q + i][s] = v0[i];
#pragma unroll
    for (int i = 0; i < 4; ++i) xT[8 * q + 4 + i][s] = v1[i];
  }

  // ---- P accumulators, b2 folded in (col c = 16ct+l15; ls cols log2-scaled) ----
  f32x4 acc0, acc1, acc2, acc3;
  {
    float bscale = (l15 & 1) ? KLOG2E : 1.0f;
    float b0 = b2[l15] * bscale;
    float b1v = b2[16 + l15] * bscale;
    float b2v = b2[32 + l15] * bscale;
    float b3v = b2[48 + l15] * bscale;
    acc0 = (f32x4){b0, b0, b0, b0};
    acc1 = (f32x4){b1v, b1v, b1v, b1v};
    acc2 = (f32x4){b2v, b2v, b2v, b2v};
    acc3 = (f32x4){b3v, b3v, b3v, b3v};
  }
  f32x4 lsacc = {0.f, 0.f, 0.f, 0.f};

  __syncthreads();

#pragma unroll 1
  for (int t = 0; t < 32; ++t) {
    // ---- EMIT dim t: cols 2t (shift) / 2t+1 (ls) live in acc tile t>>3 ----
    {
      int cte = t >> 3;
      int li = 2 * (t & 7);
      f32x4 av = (cte == 0) ? acc0 : (cte == 1) ? acc1 : (cte == 2) ? acc2 : acc3;
      f32x4 pv;
#pragma unroll
      for (int r = 0; r < 4; ++r) pv[r] = __shfl_xor(av[r], 1);
      if (l15 == li) {                       // shift lanes: partner = ls (log2)
        f32x4 x4 = *reinterpret_cast<const f32x4*>(&xT[t][16 * w + 4 * lk]);
#pragma unroll
        for (int r = 0; r < 4; ++r) {
          float yv = fmaf(x4[r], __builtin_amdgcn_exp2f(pv[r]), av[r]);
          ybf[16 * w + 4 * lk + r][t] = f2bf(yv);
          out[(size_t)(s0 + 16 * w + 4 * lk + r) * 32 + t] = yv;
        }
        lsacc += pv;
      }
    }
    __syncthreads();                         // ybf[t] visible to all GEMM1 reads

    if (t < 31) {
      const int g = t;                       // hid group deg = g+1
      const int cnt = (g == 0) ? 34 : 33;
      short8 yB  = *reinterpret_cast<const short8*>(&ybf[16 * w + l15][8 * lk]);
      short8 cB0 = *reinterpret_cast<const short8*>(&ctxb[16 * w + l15][8 * lk]);
      short8 cB1 = *reinterpret_cast<const short8*>(&ctxb[16 * w + l15][32 + 8 * lk]);
      unsigned int pa[3][2];
#pragma unroll
      for (int ht = 0; ht < 3; ++ht) {
        int j = 16 * ht + l15;
        bool vld = j < cnt;
        int h = vld ? (g + 31 * j) : 0;
        short8 w1A  = *reinterpret_cast<const short8*>(W1mT + (size_t)h * 32 + 8 * lk);
        short8 wcA0 = *reinterpret_cast<const short8*>(WcT + (size_t)h * 64 + 8 * lk);
        short8 wcA1 = *reinterpret_cast<const short8*>(WcT + (size_t)h * 64 + 32 + 8 * lk);
        short8 z = {0, 0, 0, 0, 0, 0, 0, 0};
        if (!vld) { w1A = z; wcA0 = z; wcA1 = z; }
        const unsigned short* bp = b1g + 64 * g + 16 * ht + 4 * lk;
        f32x4 C = {bf2f(bp[0]), bf2f(bp[1]), bf2f(bp[2]), bf2f(bp[3])};
        C = __builtin_amdgcn_mfma_f32_16x16x32_bf16(w1A, yB, C, 0, 0, 0);
        C = __builtin_amdgcn_mfma_f32_16x16x32_bf16(wcA0, cB0, C, 0, 0, 0);
        C = __builtin_amdgcn_mfma_f32_16x16x32_bf16(wcA1, cB1, C, 0, 0, 0);
        pa[ht][0] = cvt_pk_bf16(tanh_pre(C[0]), tanh_pre(C[1]));
        pa[ht][1] = cvt_pk_bf16(tanh_pre(C[2]), tanh_pre(C[3]));
      }
      // A-frags: a0 = slots 0..31 (q-perm), a1 = slots 32..47 + zero pad
      union { unsigned int u[4]; short8 s; } a0, a1;
      a0.u[0] = pa[0][0]; a0.u[1] = pa[0][1];
      a0.u[2] = pa[1][0]; a0.u[3] = pa[1][1];
      a1.u[0] = pa[2][0]; a1.u[1] = pa[2][1];
      a1.u[2] = 0;        a1.u[3] = 0;
#define PACC(CT, ACC)                                                              \
      {                                                                            \
        const unsigned short* wp = W2g + (size_t)(16 * CT + l15) * 1984 + 64 * g;  \
        short8 wb0 = *reinterpret_cast<const short8*>(wp + 8 * lk);                \
        short8 wb1 = *reinterpret_cast<const short8*>(wp + 32 + 8 * lk);           \
        ACC = __builtin_amdgcn_mfma_f32_16x16x32_bf16(a0.s, wb0, ACC, 0, 0, 0);    \
        ACC = __builtin_amdgcn_mfma_f32_16x16x32_bf16(a1.s, wb1, ACC, 0, 0, 0);    \
      }
      PACC(0, acc0)
      PACC(1, acc1)
      PACC(2, acc2)
      PACC(3, acc3)
#undef PACC
      __syncthreads();                       // WAR: ybf reads done before next emit
    }
  }

  // ---- log_det: each even-l15 lane holds 4 dims' ls for its 4 samples ----
  {
    f32x4 v = lsacc;
#pragma unroll
    for (int off = 2; off <= 8; off <<= 1)
#pragma unroll
      for (int r = 0; r < 4; ++r) v[r] += __shfl_xor(v[r], off);
    if (l15 == 0) {
#pragma unroll
      for (int r = 0; r < 4; ++r)
        out[(size_t)NS * 32 + s0 + 16 * w + 4 * lk + r] = v[r] * KLN2;
    }
  }
}

extern "C" void kernel_launch(void* const* d_in, const int* in_sizes, int n_in,
                              void* d_out, int out_size, void* d_ws, size_t ws_size,
                              hipStream_t stream) {
  (void)in_sizes; (void)n_in; (void)out_size; (void)ws_size;
  const float* x   = (const float*)d_in[0];
  const float* ctx = (const float*)d_in[1];
  const float* W1  = (const float*)d_in[2];
  const float* b1  = (const float*)d_in[3];
  const float* Wc  = (const float*)d_in[4];
  const float* W2  = (const float*)d_in[5];
  const float* b2  = (const float*)d_in[6];
  unsigned short* ws = (unsigned short*)d_ws;
  float* out = (float*)d_out;

  maf_prep<<<888, 256, 0, stream>>>(W1, Wc, W2, b1, ws);
  maf_main<<<256, 1024, 0, stream>>>(x, ctx, b2, ws, out);
}

// Round 16
// 216.772 us; speedup vs baseline: 3.8754x; 1.0608x over previous
//
#include <hip/hip_runtime.h>

// MAF forward, single-pass autoregressive. N=65536, D=32, H=1024, C=64.
// R15 = R14 (single emit+accumulate pass, P in MFMA accumulators, W2 degree-
//   bucketed + q-permuted, 32x fewer tanh / ~16x fewer FLOPs than the scan)
//   with ALL barriers removed: every LDS structure (ybf, ctxb, xT) is
//   wave-private (GEMM1 reads only rows 16w..16w+15 = rows emit writes; staging
//   s=tid>>2 is wave-aligned; P is in registers). Same-wave DS ordering makes
//   emit-write -> gemm-read safe without fences. 16 waves free-run -> per-step
//   latency (L2 weight loads, LDS chains, store completion) overlaps across
//   waves instead of compounding at 64 barrier convergences.
// ws layout (bf16 u16):
//   [0      ..  32768)  W1mT [h=1024][d=32] = W1[d][h]*mask1 * 2log2e
//   [32768  ..  98304)  WcT  [h=1024][c=64] = Wc[c][h] * 2log2e
//   [98304  .. 225280)  W2g  [c=64][g=31][kw=64]  degree-bucketed, q-permuted,
//                       zero-padded; ls cols * log2e
//   [225280 .. 227264)  b1g  [g=31][slot=64] bf16 = b1[h]*2log2e (0 pads)

#define NS 65536
#define K2LOG2E 2.885390082f
#define KLOG2E 1.4426950408889634f
#define KLN2 0.6931471805599453f

typedef __attribute__((ext_vector_type(8))) short short8;
typedef __attribute__((ext_vector_type(4))) float f32x4;

__device__ inline unsigned short f2bf(float f) {
  unsigned int u = __builtin_bit_cast(unsigned int, f);
  u += 0x7fffu + ((u >> 16) & 1u);          // RNE
  return (unsigned short)(u >> 16);
}
__device__ inline unsigned int cvt_pk_bf16(float lo, float hi) {
  unsigned int r;
  asm("v_cvt_pk_bf16_f32 %0, %1, %2" : "=v"(r) : "v"(lo), "v"(hi));
  return r;
}
__device__ inline float bf2f(unsigned short s) {
  return __builtin_bit_cast(float, (unsigned int)s << 16);
}
// input pre-scaled by 2log2e: tanh = 1 - 2/(1+exp2(z))
__device__ inline float tanh_pre(float z) {
  float t = __builtin_amdgcn_exp2f(z);
  float r = __builtin_amdgcn_rcpf(t + 1.0f);
  return fmaf(-2.0f, r, 1.0f);
}

__global__ void maf_prep(const float* __restrict__ W1, const float* __restrict__ Wc,
                         const float* __restrict__ W2, const float* __restrict__ b1,
                         unsigned short* __restrict__ ws) {
  int t = blockIdx.x * blockDim.x + threadIdx.x;
  if (t < 32768) {                                   // W1mT [h][d], masked+scaled
    int h = t >> 5, d = t & 31;
    int deg = h % 31 + 1;
    float v = (deg >= d + 1) ? W1[(size_t)d * 1024 + h] * K2LOG2E : 0.f;
    ws[t] = f2bf(v);
  } else if (t < 98304) {                            // WcT [h][c], scaled
    int i = t - 32768;
    int h = i >> 6, c = i & 63;
    ws[t] = f2bf(Wc[(size_t)c * 1024 + h] * K2LOG2E);
  } else if (t < 225280) {                           // W2g [c][g][kw]
    int i = t - 98304;
    int c = i / 1984, kpos = i % 1984;
    int g = kpos >> 6, kw = kpos & 63;
    int m = kw >> 5, rem = kw & 31;
    int lkk = rem >> 3, jp = (rem >> 2) & 1, r = rem & 3;
    int slot = (2 * m + jp) * 16 + 4 * lkk + r;      // q-perm -> slot within group
    int cnt = (g == 0) ? 34 : 33;
    float v = 0.f;
    if (slot < cnt) {
      int h = g + 31 * slot;                         // deg(h) == g+1
      int d = c >> 1;
      if (d > g) {                                   // mask2: out_deg > hid_deg
        v = W2[(size_t)h * 64 + c];
        if (c & 1) v *= KLOG2E;                      // ls cols in log2 domain
      }
    }
    ws[t] = f2bf(v);
  } else if (t < 227264) {                           // b1g [g][slot]
    int i = t - 225280;
    int g = i >> 6, slot = i & 63;
    int cnt = (g == 0) ? 34 : 33;
    float v = (slot < cnt) ? b1[g + 31 * slot] * K2LOG2E : 0.f;
    ws[t] = f2bf(v);
  }
}

__global__ __launch_bounds__(1024, 4) void maf_main(
    const float* __restrict__ x, const float* __restrict__ ctx,
    const float* __restrict__ b2, const unsigned short* __restrict__ ws,
    float* __restrict__ out)
{
  // LDS: 20480 + 36864 + 33280 = 90624 B -> 1 block/CU. All wave-private.
  __shared__ __align__(16) unsigned short ybf[256][40];   // y bf16 [s][d]
  __shared__ __align__(16) unsigned short ctxb[256][72];  // ctx bf16 [s][c]
  __shared__ __align__(16) float xT[32][260];             // x transposed [d][s]

  const unsigned short* W1mT = ws;             // [1024][32]
  const unsigned short* WcT  = ws + 32768;     // [1024][64]
  const unsigned short* W2g  = ws + 98304;     // [64][1984]
  const unsigned short* b1g  = ws + 225280;    // [1984]

  const int tid  = threadIdx.x;
  const int lane = tid & 63;
  const int w    = tid >> 6;        // wave 0..15: owns samples [16w, 16w+16)
  const int l15  = lane & 15;
  const int lk   = lane >> 4;
  const int s0   = blockIdx.x * 256;

  // ---- stage (all wave-private; no barriers anywhere) ----
  // zero own ybf rows: 16 rows x 40 shorts = 320 u32
  {
    unsigned int* yb32 = reinterpret_cast<unsigned int*>(&ybf[16 * w][0]);
    for (int i = lane; i < 320; i += 64) yb32[i] = 0u;
  }
  // ctx (f32 -> bf16): thread stages sample tid>>2 (wave-aligned)
  {
    int s = tid >> 2, q = tid & 3;
    const float* cp = ctx + (size_t)(s0 + s) * 64 + 16 * q;
    unsigned int pk[8];
#pragma unroll
    for (int i = 0; i < 4; ++i) {
      f32x4 v = *reinterpret_cast<const f32x4*>(cp + 4 * i);
      pk[2 * i]     = cvt_pk_bf16(v[0], v[1]);
      pk[2 * i + 1] = cvt_pk_bf16(v[2], v[3]);
    }
    unsigned int* dst = reinterpret_cast<unsigned int*>(&ctxb[s][16 * q]);
#pragma unroll
    for (int i = 0; i < 8; ++i) dst[i] = pk[i];
  }
  // xT
  {
    int s = tid >> 2, q = tid & 3;
    const float* xp = x + (size_t)(s0 + s) * 32 + 8 * q;
    f32x4 v0 = *reinterpret_cast<const f32x4*>(xp);
    f32x4 v1 = *reinterpret_cast<const f32x4*>(xp + 4);
#pragma unroll
    for (int i = 0; i < 4; ++i) xT[8 * q + i][s] = v0[i];
#pragma unroll
    for (int i = 0; i < 4; ++i) xT[8 * q + 4 + i][s] = v1[i];
  }

  // ---- P accumulators, b2 folded in (col c = 16ct+l15; ls cols log2-scaled) ----
  f32x4 acc0, acc1, acc2, acc3;
  {
    float bscale = (l15 & 1) ? KLOG2E : 1.0f;
    float b0 = b2[l15] * bscale;
    float b1v = b2[16 + l15] * bscale;
    float b2v = b2[32 + l15] * bscale;
    float b3v = b2[48 + l15] * bscale;
    acc0 = (f32x4){b0, b0, b0, b0};
    acc1 = (f32x4){b1v, b1v, b1v, b1v};
    acc2 = (f32x4){b2v, b2v, b2v, b2v};
    acc3 = (f32x4){b3v, b3v, b3v, b3v};
  }
  f32x4 lsacc = {0.f, 0.f, 0.f, 0.f};

#pragma unroll 1
  for (int t = 0; t < 32; ++t) {
    // ---- EMIT dim t: cols 2t (shift) / 2t+1 (ls) live in acc tile t>>3 ----
    {
      int cte = t >> 3;
      int li = 2 * (t & 7);
      f32x4 av = (cte == 0) ? acc0 : (cte == 1) ? acc1 : (cte == 2) ? acc2 : acc3;
      f32x4 pv;
#pragma unroll
      for (int r = 0; r < 4; ++r) pv[r] = __shfl_xor(av[r], 1);
      if (l15 == li) {                       // shift lanes: partner = ls (log2)
        f32x4 x4 = *reinterpret_cast<const f32x4*>(&xT[t][16 * w + 4 * lk]);
#pragma unroll
        for (int r = 0; r < 4; ++r) {
          float yv = fmaf(x4[r], __builtin_amdgcn_exp2f(pv[r]), av[r]);
          ybf[16 * w + 4 * lk + r][t] = f2bf(yv);
          out[(size_t)(s0 + 16 * w + 4 * lk + r) * 32 + t] = yv;
        }
        lsacc += pv;
      }
    }
    // no fence needed: same-wave DS write->read is ordered; ybf rows wave-private

    if (t < 31) {
      const int g = t;                       // hid group deg = g+1
      const int cnt = (g == 0) ? 34 : 33;
      short8 yB  = *reinterpret_cast<const short8*>(&ybf[16 * w + l15][8 * lk]);
      short8 cB0 = *reinterpret_cast<const short8*>(&ctxb[16 * w + l15][8 * lk]);
      short8 cB1 = *reinterpret_cast<const short8*>(&ctxb[16 * w + l15][32 + 8 * lk]);
      unsigned int pa[3][2];
#pragma unroll
      for (int ht = 0; ht < 3; ++ht) {
        int j = 16 * ht + l15;
        bool vld = j < cnt;
        int h = vld ? (g + 31 * j) : 0;
        short8 w1A  = *reinterpret_cast<const short8*>(W1mT + (size_t)h * 32 + 8 * lk);
        short8 wcA0 = *reinterpret_cast<const short8*>(WcT + (size_t)h * 64 + 8 * lk);
        short8 wcA1 = *reinterpret_cast<const short8*>(WcT + (size_t)h * 64 + 32 + 8 * lk);
        short8 z = {0, 0, 0, 0, 0, 0, 0, 0};
        if (!vld) { w1A = z; wcA0 = z; wcA1 = z; }
        const unsigned short* bp = b1g + 64 * g + 16 * ht + 4 * lk;
        f32x4 C = {bf2f(bp[0]), bf2f(bp[1]), bf2f(bp[2]), bf2f(bp[3])};
        C = __builtin_amdgcn_mfma_f32_16x16x32_bf16(w1A, yB, C, 0, 0, 0);
        C = __builtin_amdgcn_mfma_f32_16x16x32_bf16(wcA0, cB0, C, 0, 0, 0);
        C = __builtin_amdgcn_mfma_f32_16x16x32_bf16(wcA1, cB1, C, 0, 0, 0);
        pa[ht][0] = cvt_pk_bf16(tanh_pre(C[0]), tanh_pre(C[1]));
        pa[ht][1] = cvt_pk_bf16(tanh_pre(C[2]), tanh_pre(C[3]));
      }
      // A-frags: a0 = slots 0..31 (q-perm), a1 = slots 32..47 + zero pad
      union { unsigned int u[4]; short8 s; } a0, a1;
      a0.u[0] = pa[0][0]; a0.u[1] = pa[0][1];
      a0.u[2] = pa[1][0]; a0.u[3] = pa[1][1];
      a1.u[0] = pa[2][0]; a1.u[1] = pa[2][1];
      a1.u[2] = 0;        a1.u[3] = 0;
#define PACC(CT, ACC)                                                              \
      {                                                                            \
        const unsigned short* wp = W2g + (size_t)(16 * CT + l15) * 1984 + 64 * g;  \
        short8 wb0 = *reinterpret_cast<const short8*>(wp + 8 * lk);                \
        short8 wb1 = *reinterpret_cast<const short8*>(wp + 32 + 8 * lk);           \
        ACC = __builtin_amdgcn_mfma_f32_16x16x32_bf16(a0.s, wb0, ACC, 0, 0, 0);    \
        ACC = __builtin_amdgcn_mfma_f32_16x16x32_bf16(a1.s, wb1, ACC, 0, 0, 0);    \
      }
      PACC(0, acc0)
      PACC(1, acc1)
      PACC(2, acc2)
      PACC(3, acc3)
#undef PACC
    }
  }

  // ---- log_det: each even-l15 lane holds 4 dims' ls for its 4 samples ----
  {
    f32x4 v = lsacc;
#pragma unroll
    for (int off = 2; off <= 8; off <<= 1)
#pragma unroll
      for (int r = 0; r < 4; ++r) v[r] += __shfl_xor(v[r], off);
    if (l15 == 0) {
#pragma unroll
      for (int r = 0; r < 4; ++r)
        out[(size_t)NS * 32 + s0 + 16 * w + 4 * lk + r] = v[r] * KLN2;
    }
  }
}

extern "C" void kernel_launch(void* const* d_in, const int* in_sizes, int n_in,
                              void* d_out, int out_size, void* d_ws, size_t ws_size,
                              hipStream_t stream) {
  (void)in_sizes; (void)n_in; (void)out_size; (void)ws_size;
  const float* x   = (const float*)d_in[0];
  const float* ctx = (const float*)d_in[1];
  const float* W1  = (const float*)d_in[2];
  const float* b1  = (const float*)d_in[3];
  const float* Wc  = (const float*)d_in[4];
  const float* W2  = (const float*)d_in[5];
  const float* b2  = (const float*)d_in[6];
  unsigned short* ws = (unsigned short*)d_ws;
  float* out = (float*)d_out;

  maf_prep<<<888, 256, 0, stream>>>(W1, Wc, W2, b1, ws);
  maf_main<<<256, 1024, 0, stream>>>(x, ctx, b2, ws, out);
}

// Round 17
// 117.813 us; speedup vs baseline: 7.1305x; 1.8400x over previous
//
#include <hip/hip_runtime.h>

// MAF forward, single-pass autoregressive. N=65536, D=32, H=1024, C=64.
// R16 = R15 (single emit+accumulate pass, P in MFMA accumulators, W2 degree-
//   bucketed + q-permuted, barrier-free) with the per-step latency chain attacked:
//   - 2 sample-tiles per wave (32 samples/wave): every weight load feeds 2x the
//     samples (halves per-CU L1 replication) and doubles per-wave MFMA ILP.
//   - cross-iteration register prefetch (ping-pong WA/WB) of W1/Wc fragments:
//     next step's first-phase loads issue before this step's compute.
//   - ctx in registers (ctxb LDS deleted); all remaining LDS wave-private.
//   8 waves x 512 thr x 256 blocks (1 blk/CU, 2 waves/SIMD, 256-VGPR cap).
// ws layout (bf16 u16):
//   [0      ..  32768)  W1mT [h=1024][d=32] = W1[d][h]*mask1 * 2log2e
//   [32768  ..  98304)  WcT  [h=1024][c=64] = Wc[c][h] * 2log2e
//   [98304  .. 225280)  W2g  [c=64][g=31][kw=64] degree-bucketed, q-permuted,
//                       zero-padded; ls cols * log2e
//   [225280 .. 227264)  b1g  [g=31][slot=64] bf16 = b1[h]*2log2e (0 pads)

#define NS 65536
#define K2LOG2E 2.885390082f
#define KLOG2E 1.4426950408889634f
#define KLN2 0.6931471805599453f

typedef __attribute__((ext_vector_type(8))) short short8;
typedef __attribute__((ext_vector_type(4))) float f32x4;

__device__ inline unsigned short f2bf(float f) {
  unsigned int u = __builtin_bit_cast(unsigned int, f);
  u += 0x7fffu + ((u >> 16) & 1u);          // RNE
  return (unsigned short)(u >> 16);
}
__device__ inline unsigned int cvt_pk_bf16(float lo, float hi) {
  unsigned int r;
  asm("v_cvt_pk_bf16_f32 %0, %1, %2" : "=v"(r) : "v"(lo), "v"(hi));
  return r;
}
__device__ inline float bf2f(unsigned short s) {
  return __builtin_bit_cast(float, (unsigned int)s << 16);
}
// input pre-scaled by 2log2e: tanh = 1 - 2/(1+exp2(z))
__device__ inline float tanh_pre(float z) {
  float t = __builtin_amdgcn_exp2f(z);
  float r = __builtin_amdgcn_rcpf(t + 1.0f);
  return fmaf(-2.0f, r, 1.0f);
}
__device__ inline short8 ld8bf(const float* p) {
  f32x4 a = *reinterpret_cast<const f32x4*>(p);
  f32x4 b = *reinterpret_cast<const f32x4*>(p + 4);
  union { short8 s; unsigned int u[4]; } t;
  t.u[0] = cvt_pk_bf16(a[0], a[1]);
  t.u[1] = cvt_pk_bf16(a[2], a[3]);
  t.u[2] = cvt_pk_bf16(b[0], b[1]);
  t.u[3] = cvt_pk_bf16(b[2], b[3]);
  return t.s;
}

__global__ void maf_prep(const float* __restrict__ W1, const float* __restrict__ Wc,
                         const float* __restrict__ W2, const float* __restrict__ b1,
                         unsigned short* __restrict__ ws) {
  int t = blockIdx.x * blockDim.x + threadIdx.x;
  if (t < 32768) {                                   // W1mT [h][d], masked+scaled
    int h = t >> 5, d = t & 31;
    int deg = h % 31 + 1;
    float v = (deg >= d + 1) ? W1[(size_t)d * 1024 + h] * K2LOG2E : 0.f;
    ws[t] = f2bf(v);
  } else if (t < 98304) {                            // WcT [h][c], scaled
    int i = t - 32768;
    int h = i >> 6, c = i & 63;
    ws[t] = f2bf(Wc[(size_t)c * 1024 + h] * K2LOG2E);
  } else if (t < 225280) {                           // W2g [c][g][kw]
    int i = t - 98304;
    int c = i / 1984, kpos = i % 1984;
    int g = kpos >> 6, kw = kpos & 63;
    int m = kw >> 5, rem = kw & 31;
    int lkk = rem >> 3, jp = (rem >> 2) & 1, r = rem & 3;
    int slot = (2 * m + jp) * 16 + 4 * lkk + r;      // q-perm -> slot within group
    int cnt = (g == 0) ? 34 : 33;
    float v = 0.f;
    if (slot < cnt) {
      int h = g + 31 * slot;                         // deg(h) == g+1
      int d = c >> 1;
      if (d > g) {                                   // mask2: out_deg > hid_deg
        v = W2[(size_t)h * 64 + c];
        if (c & 1) v *= KLOG2E;                      // ls cols in log2 domain
      }
    }
    ws[t] = f2bf(v);
  } else if (t < 227264) {                           // b1g [g][slot]
    int i = t - 225280;
    int g = i >> 6, slot = i & 63;
    int cnt = (g == 0) ? 34 : 33;
    float v = (slot < cnt) ? b1[g + 31 * slot] * K2LOG2E : 0.f;
    ws[t] = f2bf(v);
  }
}

__global__ __launch_bounds__(512, 2) void maf_main(
    const float* __restrict__ x, const float* __restrict__ ctx,
    const float* __restrict__ b2, const unsigned short* __restrict__ ws,
    float* __restrict__ out)
{
  // LDS: 20480 + 33792 = 54272 B. All wave-private; zero barriers.
  __shared__ __align__(16) unsigned short ybf[256][40];   // y bf16 [s][d]
  __shared__ __align__(16) float xT[32][264];             // x transposed [d][s]

  const unsigned short* W1mT = ws;             // [1024][32]
  const unsigned short* WcT  = ws + 32768;     // [1024][64]
  const unsigned short* W2g  = ws + 98304;     // [64][1984]
  const unsigned short* b1g  = ws + 225280;    // [1984]

  const int tid  = threadIdx.x;
  const int lane = tid & 63;
  const int w    = tid >> 6;        // wave 0..7: owns samples [32w, 32w+32)
  const int l15  = lane & 15;
  const int lk   = lane >> 4;
  const int s0   = blockIdx.x * 256;
  const int sw   = 32 * w;

  // ---- zero own ybf rows (32 rows x 40 u16 = 640 u32) ----
  {
    unsigned int* p = reinterpret_cast<unsigned int*>(&ybf[sw][0]);
    for (int i = lane; i < 640; i += 64) p[i] = 0u;
  }
  // ---- xT staging (wave-private: thread stages sample tid>>1) ----
  {
    int s = tid >> 1, q = tid & 1;
    const float* xp = x + (size_t)(s0 + s) * 32 + 16 * q;
    f32x4 v0 = *reinterpret_cast<const f32x4*>(xp);
    f32x4 v1 = *reinterpret_cast<const f32x4*>(xp + 4);
    f32x4 v2 = *reinterpret_cast<const f32x4*>(xp + 8);
    f32x4 v3 = *reinterpret_cast<const f32x4*>(xp + 12);
#pragma unroll
    for (int i = 0; i < 4; ++i) {
      xT[16 * q + i][s]      = v0[i];
      xT[16 * q + 4 + i][s]  = v1[i];
      xT[16 * q + 8 + i][s]  = v2[i];
      xT[16 * q + 12 + i][s] = v3[i];
    }
  }
  // ---- ctx -> registers (per tile; one-time) ----
  short8 cB0_t0, cB1_t0, cB0_t1, cB1_t1;
  {
    const float* c0 = ctx + (size_t)(s0 + sw + l15) * 64;
    const float* c1 = ctx + (size_t)(s0 + sw + 16 + l15) * 64;
    cB0_t0 = ld8bf(c0 + 8 * lk);
    cB1_t0 = ld8bf(c0 + 32 + 8 * lk);
    cB0_t1 = ld8bf(c1 + 8 * lk);
    cB1_t1 = ld8bf(c1 + 32 + 8 * lk);
  }

  // ---- P accumulators (b2 folded; ls cols log2-scaled) ----
  f32x4 acc0_0, acc0_1, acc0_2, acc0_3, acc1_0, acc1_1, acc1_2, acc1_3;
  {
    float bs = (l15 & 1) ? KLOG2E : 1.0f;
    float v0 = b2[l15] * bs, v1 = b2[16 + l15] * bs;
    float v2 = b2[32 + l15] * bs, v3 = b2[48 + l15] * bs;
    acc0_0 = (f32x4){v0, v0, v0, v0}; acc1_0 = acc0_0;
    acc0_1 = (f32x4){v1, v1, v1, v1}; acc1_1 = acc0_1;
    acc0_2 = (f32x4){v2, v2, v2, v2}; acc1_2 = acc0_2;
    acc0_3 = (f32x4){v3, v3, v3, v3}; acc1_3 = acc0_3;
  }
  f32x4 ls0 = {0.f, 0.f, 0.f, 0.f}, ls1 = {0.f, 0.f, 0.f, 0.f};

#define LOADW(P, G) {                                                             \
    const int gg_ = (G);                                                          \
    const int cnt_ = (gg_ == 0) ? 34 : 33;                                        \
    _Pragma("unroll")                                                             \
    for (int ht = 0; ht < 3; ++ht) {                                              \
      int j_ = 16 * ht + l15;                                                     \
      bool vld_ = j_ < cnt_;                                                      \
      int h_ = vld_ ? (gg_ + 31 * j_) : 0;                                        \
      short8 a1_ = *reinterpret_cast<const short8*>(W1mT + (size_t)h_ * 32 + 8 * lk); \
      short8 a2_ = *reinterpret_cast<const short8*>(WcT + (size_t)h_ * 64 + 8 * lk);  \
      short8 a3_ = *reinterpret_cast<const short8*>(WcT + (size_t)h_ * 64 + 32 + 8 * lk); \
      short8 z_ = {0, 0, 0, 0, 0, 0, 0, 0};                                       \
      if (!vld_) { a1_ = z_; a2_ = z_; a3_ = z_; }                                \
      P##_w1[ht] = a1_; P##_c0[ht] = a2_; P##_c1[ht] = a3_;                       \
    } }

#define COMPUTE(P, G) {                                                           \
    const int gg_ = (G);                                                          \
    short8 w2b[4][2];                                                             \
    _Pragma("unroll")                                                             \
    for (int ct = 0; ct < 4; ++ct) {                                              \
      const unsigned short* wp_ = W2g + (size_t)(16 * ct + l15) * 1984 + 64 * gg_; \
      w2b[ct][0] = *reinterpret_cast<const short8*>(wp_ + 8 * lk);                \
      w2b[ct][1] = *reinterpret_cast<const short8*>(wp_ + 32 + 8 * lk);           \
    }                                                                             \
    short8 yB0_ = *reinterpret_cast<const short8*>(&ybf[sw + l15][8 * lk]);       \
    short8 yB1_ = *reinterpret_cast<const short8*>(&ybf[sw + 16 + l15][8 * lk]);  \
    unsigned int pa0[3][2], pa1[3][2];                                            \
    _Pragma("unroll")                                                             \
    for (int ht = 0; ht < 3; ++ht) {                                              \
      const unsigned short* bp_ = b1g + 64 * gg_ + 16 * ht + 4 * lk;              \
      f32x4 CI = {bf2f(bp_[0]), bf2f(bp_[1]), bf2f(bp_[2]), bf2f(bp_[3])};        \
      f32x4 C0 = __builtin_amdgcn_mfma_f32_16x16x32_bf16(P##_w1[ht], yB0_, CI, 0, 0, 0); \
      C0 = __builtin_amdgcn_mfma_f32_16x16x32_bf16(P##_c0[ht], cB0_t0, C0, 0, 0, 0);     \
      C0 = __builtin_amdgcn_mfma_f32_16x16x32_bf16(P##_c1[ht], cB1_t0, C0, 0, 0, 0);     \
      f32x4 C1 = __builtin_amdgcn_mfma_f32_16x16x32_bf16(P##_w1[ht], yB1_, CI, 0, 0, 0); \
      C1 = __builtin_amdgcn_mfma_f32_16x16x32_bf16(P##_c0[ht], cB0_t1, C1, 0, 0, 0);     \
      C1 = __builtin_amdgcn_mfma_f32_16x16x32_bf16(P##_c1[ht], cB1_t1, C1, 0, 0, 0);     \
      pa0[ht][0] = cvt_pk_bf16(tanh_pre(C0[0]), tanh_pre(C0[1]));                 \
      pa0[ht][1] = cvt_pk_bf16(tanh_pre(C0[2]), tanh_pre(C0[3]));                 \
      pa1[ht][0] = cvt_pk_bf16(tanh_pre(C1[0]), tanh_pre(C1[1]));                 \
      pa1[ht][1] = cvt_pk_bf16(tanh_pre(C1[2]), tanh_pre(C1[3]));                 \
    }                                                                             \
    union { unsigned int u[4]; short8 s; } A0t0_, A1t0_, A0t1_, A1t1_;            \
    A0t0_.u[0] = pa0[0][0]; A0t0_.u[1] = pa0[0][1];                               \
    A0t0_.u[2] = pa0[1][0]; A0t0_.u[3] = pa0[1][1];                               \
    A1t0_.u[0] = pa0[2][0]; A1t0_.u[1] = pa0[2][1]; A1t0_.u[2] = 0; A1t0_.u[3] = 0; \
    A0t1_.u[0] = pa1[0][0]; A0t1_.u[1] = pa1[0][1];                               \
    A0t1_.u[2] = pa1[1][0]; A0t1_.u[3] = pa1[1][1];                               \
    A1t1_.u[0] = pa1[2][0]; A1t1_.u[1] = pa1[2][1]; A1t1_.u[2] = 0; A1t1_.u[3] = 0; \
    PACC2(0) PACC2(1) PACC2(2) PACC2(3)                                           \
  }

#define PACC2(CT)                                                                 \
    acc0_##CT = __builtin_amdgcn_mfma_f32_16x16x32_bf16(A0t0_.s, w2b[CT][0], acc0_##CT, 0, 0, 0); \
    acc0_##CT = __builtin_amdgcn_mfma_f32_16x16x32_bf16(A1t0_.s, w2b[CT][1], acc0_##CT, 0, 0, 0); \
    acc1_##CT = __builtin_amdgcn_mfma_f32_16x16x32_bf16(A0t1_.s, w2b[CT][0], acc1_##CT, 0, 0, 0); \
    acc1_##CT = __builtin_amdgcn_mfma_f32_16x16x32_bf16(A1t1_.s, w2b[CT][1], acc1_##CT, 0, 0, 0);

#define EMIT(T) {                                                                 \
    const int t_ = (T);                                                           \
    const int cte_ = t_ >> 3;                                                     \
    const int li_ = 2 * (t_ & 7);                                                 \
    f32x4 av0 = cte_ == 0 ? acc0_0 : cte_ == 1 ? acc0_1 : cte_ == 2 ? acc0_2 : acc0_3; \
    f32x4 av1 = cte_ == 0 ? acc1_0 : cte_ == 1 ? acc1_1 : cte_ == 2 ? acc1_2 : acc1_3; \
    f32x4 pv0, pv1;                                                               \
    _Pragma("unroll")                                                             \
    for (int r = 0; r < 4; ++r) {                                                 \
      pv0[r] = __shfl_xor(av0[r], 1);                                             \
      pv1[r] = __shfl_xor(av1[r], 1);                                             \
    }                                                                             \
    if (l15 == li_) {                                                             \
      f32x4 x40 = *reinterpret_cast<const f32x4*>(&xT[t_][sw + 4 * lk]);          \
      f32x4 x41 = *reinterpret_cast<const f32x4*>(&xT[t_][sw + 16 + 4 * lk]);     \
      _Pragma("unroll")                                                           \
      for (int r = 0; r < 4; ++r) {                                               \
        float y0 = fmaf(x40[r], __builtin_amdgcn_exp2f(pv0[r]), av0[r]);          \
        float y1 = fmaf(x41[r], __builtin_amdgcn_exp2f(pv1[r]), av1[r]);          \
        ybf[sw + 4 * lk + r][t_] = f2bf(y0);                                      \
        ybf[sw + 16 + 4 * lk + r][t_] = f2bf(y1);                                 \
        out[(size_t)(s0 + sw + 4 * lk + r) * 32 + t_] = y0;                       \
        out[(size_t)(s0 + sw + 16 + 4 * lk + r) * 32 + t_] = y1;                  \
      }                                                                           \
      ls0 += pv0; ls1 += pv1;                                                     \
    } }

  // ---- ping-pong weight sets ----
  short8 WA_w1[3], WA_c0[3], WA_c1[3];
  short8 WB_w1[3], WB_c0[3], WB_c1[3];
  LOADW(WA, 0)

#pragma unroll 1
  for (int t = 0; t < 30; t += 2) {
    EMIT(t)
    LOADW(WB, t + 1)
    COMPUTE(WA, t)
    EMIT(t + 1)
    LOADW(WA, t + 2)
    COMPUTE(WB, t + 1)
  }
  EMIT(30)
  COMPUTE(WA, 30)
  EMIT(31)

  // ---- log_det: sum over even-l15 lanes (bits 1..3 of lane) ----
  {
    f32x4 v0 = ls0, v1 = ls1;
#pragma unroll
    for (int off = 2; off <= 8; off <<= 1)
#pragma unroll
      for (int r = 0; r < 4; ++r) {
        v0[r] += __shfl_xor(v0[r], off);
        v1[r] += __shfl_xor(v1[r], off);
      }
    if (l15 == 0) {
#pragma unroll
      for (int r = 0; r < 4; ++r) {
        out[(size_t)NS * 32 + s0 + sw + 4 * lk + r]      = v0[r] * KLN2;
        out[(size_t)NS * 32 + s0 + sw + 16 + 4 * lk + r] = v1[r] * KLN2;
      }
    }
  }
}

extern "C" void kernel_launch(void* const* d_in, const int* in_sizes, int n_in,
                              void* d_out, int out_size, void* d_ws, size_t ws_size,
                              hipStream_t stream) {
  (void)in_sizes; (void)n_in; (void)out_size; (void)ws_size;
  const float* x   = (const float*)d_in[0];
  const float* ctx = (const float*)d_in[1];
  const float* W1  = (const float*)d_in[2];
  const float* b1  = (const float*)d_in[3];
  const float* Wc  = (const float*)d_in[4];
  const float* W2  = (const float*)d_in[5];
  const float* b2  = (const float*)d_in[6];
  unsigned short* ws = (unsigned short*)d_ws;
  float* out = (float*)d_out;

  maf_prep<<<888, 256, 0, stream>>>(W1, Wc, W2, b1, ws);
  maf_main<<<256, 512, 0, stream>>>(x, ctx, b2, ws, out);
}